// Round 21
// baseline (125.135 us; speedup 1.0000x reference)
//
#include <hip/hip_runtime.h>
#include <hip/hip_bf16.h>

#define B_ 4
#define Q_ 256
#define K_ 1024
#define D_ 256
#define NVPAD 768
#define LOG2E 1.44269504f

__device__ __forceinline__ float fexp2(float x) {
    float r; asm("v_exp_f32 %0, %1" : "=v"(r) : "v"(x)); return r;
}
__device__ __forceinline__ float frcp(float x) {
    float r; asm("v_rcp_f32 %0, %1" : "=v"(r) : "v"(x)); return r;
}

// Grid = B, 64 threads. kidx[slot]=k, nvalid. (Separate launch: proj reads kidx.)
__global__ void compact_kernel(const int* __restrict__ mask,
                               ushort* __restrict__ kidx,
                               int* __restrict__ nvalid) {
    const int b = blockIdx.x, lane = threadIdx.x;
    const int* m = mask + b * K_;
    const int base = lane * 16;
    int cnt = 0;
#pragma unroll
    for (int i = 0; i < 16; ++i) cnt += (m[base + i] != 0);
    int inc = cnt;
#pragma unroll
    for (int d = 1; d < 64; d <<= 1) {
        int tt = __shfl_up(inc, d);
        if (lane >= d) inc += tt;
    }
    const int total = __shfl(inc, 63);
    int pos = inc - cnt;
    ushort* kb = kidx + b * K_;
    for (int i = 0; i < 16; ++i) {
        int kk = base + i;
        if (m[kk] != 0) kb[pos++] = (ushort)kk;
    }
    for (int j = total + lane; j < K_; j += 64) kb[j] = 0;
    if (lane == 0) nvalid[b] = total;
}

// Grid (80,4), 256 thr.
// x<16 : q-proj rows m0=x*64 -> qpE row-major (exp2 applied).
// x>=16: k-proj over COMPACTED SLOT SPACE (gather via kidx, dense kpC write;
//        blocks with slot0 >= nv exit immediately).
__global__ __launch_bounds__(256) void proj_kernel(const float* __restrict__ q,
                                                   const float* __restrict__ k,
                                                   const float* __restrict__ Wq,
                                                   const float* __restrict__ Wk,
                                                   const ushort* __restrict__ kidx,
                                                   const int* __restrict__ nvalid,
                                                   float* __restrict__ qpE,
                                                   float* __restrict__ kpC,
                                                   float scale) {
    const int t = threadIdx.x;
    const bool isQ = blockIdx.x < 16;
    const float* A; const float* W; int m0, b = 0, nv = 0;
    __shared__ ushort s_row[64];
    if (isQ) { A = q; W = Wq; m0 = blockIdx.x * 64; }
    else {
        const int g = (blockIdx.x - 16) * 64;
        b = g >> 10;
        m0 = g & 1023;
        nv = nvalid[b];
        if (m0 >= nv) return;
        A = k; W = Wk;
        if (t < 64) s_row[t] = kidx[b * K_ + m0 + t];
    }

    __shared__ float As[16][65];
    __shared__ float Ws[16][64];
    const int tx = t & 15, ty = t >> 4;
    const int n0 = blockIdx.y * 64;
    const int ar = t >> 2, ac = (t & 3) * 4;
    const int wr = t >> 4, wc = (t & 15) * 4;
    float c[4][4] = {};
    if (!isQ) __syncthreads();
    for (int kb = 0; kb < 256; kb += 16) {
        __syncthreads();
        {
            const int src = isQ ? (m0 + ar) : (b * K_ + s_row[ar]);
            float4 av = *(const float4*)(A + (size_t)src * 256 + kb + ac);
            As[ac + 0][ar] = av.x; As[ac + 1][ar] = av.y;
            As[ac + 2][ar] = av.z; As[ac + 3][ar] = av.w;
        }
        float4 wvv = *(const float4*)(W + (size_t)(kb + wr) * 256 + n0 + wc);
        wvv.x *= scale; wvv.y *= scale; wvv.z *= scale; wvv.w *= scale;
        *(float4*)(&Ws[wr][wc]) = wvv;
        __syncthreads();
#pragma unroll
        for (int kk = 0; kk < 16; ++kk) {
            float4 bv = *(const float4*)(&Ws[kk][tx * 4]);
#pragma unroll
            for (int i = 0; i < 4; ++i) {
                float a = As[kk][ty * 4 + i];
                c[i][0] = fmaf(a, bv.x, c[i][0]);
                c[i][1] = fmaf(a, bv.y, c[i][1]);
                c[i][2] = fmaf(a, bv.z, c[i][2]);
                c[i][3] = fmaf(a, bv.w, c[i][3]);
            }
        }
    }
    if (isQ) {
#pragma unroll
        for (int i = 0; i < 4; ++i) {
            float4 o = make_float4(fexp2(c[i][0]), fexp2(c[i][1]),
                                   fexp2(c[i][2]), fexp2(c[i][3]));
            *(float4*)(qpE + (size_t)(m0 + ty * 4 + i) * 256 + n0 + tx * 4) = o;
        }
    } else {
        float* kpCb = kpC + (size_t)b * 64 * NVPAD * 4;
        const int e4 = (n0 + tx * 4) >> 2;
#pragma unroll
        for (int i = 0; i < 4; ++i) {
            const int sl = m0 + ty * 4 + i;
            if (sl < nv) {
                float4 o = make_float4(fexp2(c[i][0]), fexp2(c[i][1]),
                                       fexp2(c[i][2]), fexp2(c[i][3]));
                *(float4*)(kpCb + ((size_t)e4 * NVPAD + sl) * 4) = o;
            }
        }
    }
}

// Grid = 512 = B * 128 qpairs, 1024 threads = 16 waves -> 2 blocks/CU.
// Score mapping: LANE = SLOT, wave owns an 8-e chunk (2 passes x 2
// e4-groups). Per iter: 2 coalesced f4 loads + 16 rcp + 32 fma + 2
// ds_add_f32 (atomicAdd to s_sc; 64 consecutive slots -> conflict-free).
// NO cross-lane ops in the hot loop -> iters pipeline freely.
__global__ __launch_bounds__(1024, 2) void attn_kernel(const float* __restrict__ qpE,
                                                       const float* __restrict__ kpC,
                                                       const float* __restrict__ v,
                                                       const ushort* __restrict__ kidx_g,
                                                       const int* __restrict__ nvalid_g,
                                                       const float* __restrict__ wv,
                                                       float* __restrict__ out) {
    __shared__ float  s_sc[2][1024];      //  8 KB
    __shared__ ushort s_kidx[1024];       //  2 KB
    __shared__ float4 s_pv[32][64];       // 32 KB
    __shared__ float  s_inv[2];

    const int tid  = threadIdx.x;
    const int lane = tid & 63;
    const int wave = tid >> 6;            // 0..15

    int bid = blockIdx.x;
    bid = (bid & 7) * 64 + (bid >> 3);    // bijective XCD swizzle
    const int b  = bid >> 7;
    const int qi = bid & 127;
    const int q0 = qi * 2;
    const int nv = nvalid_g[b];
    const int iters = (nv + 63) >> 6;

    s_kidx[tid] = (tid < nv) ? kidx_g[b * K_ + tid] : (ushort)0;
    ((float2*)s_sc)[tid] = make_float2(0.f, 0.f);
    __syncthreads();

    const float4* Bp  = (const float4*)kpC + (size_t)b * 64 * NVPAD;
    const float*  A0g = qpE + ((size_t)(b * Q_ + q0) << 8);
    const float*  A1g = A0g + 256;

#pragma unroll
    for (int pass = 0; pass < 2; ++pass) {
        // wave owns e4-groups {g0, g0+1}; 16 waves x 2 passes cover all 64.
        const int g0 = pass * 32 + wave * 2;
        const int e0 = g0 * 4;
        float A0[8], A1[8], W[8];
        {
            float4 x0 = *(const float4*)(A0g + e0);
            float4 x1 = *(const float4*)(A0g + e0 + 4);
            A0[0]=x0.x; A0[1]=x0.y; A0[2]=x0.z; A0[3]=x0.w;
            A0[4]=x1.x; A0[5]=x1.y; A0[6]=x1.z; A0[7]=x1.w;
            float4 y0 = *(const float4*)(A1g + e0);
            float4 y1 = *(const float4*)(A1g + e0 + 4);
            A1[0]=y0.x; A1[1]=y0.y; A1[2]=y0.z; A1[3]=y0.w;
            A1[4]=y1.x; A1[5]=y1.y; A1[6]=y1.z; A1[7]=y1.w;
            float4 w0 = *(const float4*)(wv + e0);
            float4 w1 = *(const float4*)(wv + e0 + 4);
            W[0]=w0.x; W[1]=w0.y; W[2]=w0.z; W[3]=w0.w;
            W[4]=w1.x; W[5]=w1.y; W[6]=w1.z; W[7]=w1.w;
        }
        const float4* Bq = Bp + (size_t)g0 * NVPAD;

        for (int i = 0; i < iters; ++i) {
            const int s = i * 64 + lane;
            float4 B0 = Bq[s];                 // lane=slot -> fully coalesced
            float4 B1 = Bq[NVPAD + s];
            float a0 = 0.f, a1 = 0.f;
            a0 = fmaf(W[0], frcp(fmaf(A0[0], B0.x, 1.f)), a0);
            a1 = fmaf(W[0], frcp(fmaf(A1[0], B0.x, 1.f)), a1);
            a0 = fmaf(W[1], frcp(fmaf(A0[1], B0.y, 1.f)), a0);
            a1 = fmaf(W[1], frcp(fmaf(A1[1], B0.y, 1.f)), a1);
            a0 = fmaf(W[2], frcp(fmaf(A0[2], B0.z, 1.f)), a0);
            a1 = fmaf(W[2], frcp(fmaf(A1[2], B0.z, 1.f)), a1);
            a0 = fmaf(W[3], frcp(fmaf(A0[3], B0.w, 1.f)), a0);
            a1 = fmaf(W[3], frcp(fmaf(A1[3], B0.w, 1.f)), a1);
            a0 = fmaf(W[4], frcp(fmaf(A0[4], B1.x, 1.f)), a0);
            a1 = fmaf(W[4], frcp(fmaf(A1[4], B1.x, 1.f)), a1);
            a0 = fmaf(W[5], frcp(fmaf(A0[5], B1.y, 1.f)), a0);
            a1 = fmaf(W[5], frcp(fmaf(A1[5], B1.y, 1.f)), a1);
            a0 = fmaf(W[6], frcp(fmaf(A0[6], B1.z, 1.f)), a0);
            a1 = fmaf(W[6], frcp(fmaf(A1[6], B1.z, 1.f)), a1);
            a0 = fmaf(W[7], frcp(fmaf(A0[7], B1.w, 1.f)), a0);
            a1 = fmaf(W[7], frcp(fmaf(A1[7], B1.w, 1.f)), a1);
            if (s < nv) {
                atomicAdd(&s_sc[0][s], a0);    // ds_add_f32, conflict-free
                atomicAdd(&s_sc[1][s], a1);
            }
        }
    }
    __syncthreads();

    // ---- softmax: wave qq < 2 handles q = qq (score = -2 * accumulated) ----
    if (wave < 2) {
        const int qq = wave;
        float mx = -3.0e38f;
        for (int j = lane; j < nv; j += 64) mx = fmaxf(mx, -2.f * s_sc[qq][j]);
#pragma unroll
        for (int off = 32; off > 0; off >>= 1) mx = fmaxf(mx, __shfl_xor(mx, off));
        float sum = 0.f;
        for (int j = lane; j < nv; j += 64) {
            float e = fexp2((-2.f * s_sc[qq][j] - mx) * LOG2E);
            s_sc[qq][j] = e;
            sum += e;
        }
#pragma unroll
        for (int off = 32; off > 0; off >>= 1) sum += __shfl_xor(sum, off);
        if (lane == 0) s_inv[qq] = frcp(sum);
    }
    __syncthreads();

    // ---- PV: thread -> (d-float4 = tid&63, k stride-16 chunk = tid>>6) ----
    {
        const int dl = tid & 63;
        const int kq = tid >> 6;
        float4 o0 = {0, 0, 0, 0}, o1 = {0, 0, 0, 0};
        const float4* v4 = (const float4*)(v + ((size_t)b * K_ << 8));
        for (int k = kq; k < nv; k += 16) {
            int vr = s_kidx[k];
            float4 vv = v4[((size_t)vr << 6) + dl];
            float p0 = s_sc[0][k], p1 = s_sc[1][k];
            o0.x = fmaf(p0, vv.x, o0.x); o0.y = fmaf(p0, vv.y, o0.y);
            o0.z = fmaf(p0, vv.z, o0.z); o0.w = fmaf(p0, vv.w, o0.w);
            o1.x = fmaf(p1, vv.x, o1.x); o1.y = fmaf(p1, vv.y, o1.y);
            o1.z = fmaf(p1, vv.z, o1.z); o1.w = fmaf(p1, vv.w, o1.w);
        }
        s_pv[kq * 2 + 0][dl] = o0;
        s_pv[kq * 2 + 1][dl] = o1;
        __syncthreads();
        if (tid < 128) {
            const int qq = tid >> 6, c = tid & 63;
            float4 s = {0, 0, 0, 0};
#pragma unroll
            for (int g = 0; g < 16; ++g) {
                float4 x = s_pv[g * 2 + qq][c];
                s.x += x.x; s.y += x.y; s.z += x.z; s.w += x.w;
            }
            const float inv = s_inv[qq];
            s.x *= inv; s.y *= inv; s.z *= inv; s.w *= inv;
            ((float4*)out)[((size_t)(b * Q_ + q0 + qq) << 6) + c] = s;
        }
    }
}

extern "C" void kernel_launch(void* const* d_in, const int* in_sizes, int n_in,
                              void* d_out, int out_size, void* d_ws, size_t ws_size,
                              hipStream_t stream) {
    const float* q    = (const float*)d_in[0];
    const float* k    = (const float*)d_in[1];
    const float* v    = (const float*)d_in[2];
    const int*   mask = (const int*)d_in[3];
    const float* Wq   = (const float*)d_in[4];
    const float* Wk   = (const float*)d_in[5];
    const float* wv   = (const float*)d_in[6];
    float* out = (float*)d_out;

    float* qpE    = (float*)d_ws;                            // 1 MB
    float* kpC    = qpE + (size_t)B_ * Q_ * D_;              // 3 MB
    ushort* kidx  = (ushort*)(kpC + (size_t)B_ * 64 * NVPAD * 4); // 8 KB
    int* nvalid   = (int*)(kidx + (size_t)B_ * K_);          // 16 B

    const float c2 = 2.885390082f;  // 2*log2(e)

    compact_kernel<<<dim3(B_), 64, 0, stream>>>(mask, kidx, nvalid);
    proj_kernel<<<dim3(80, 4), 256, 0, stream>>>(q, k, Wq, Wk, kidx, nvalid, qpE, kpC, c2);
    attn_kernel<<<dim3(512), 1024, 0, stream>>>(qpE, kpC, v, kidx, nvalid, wv, out);
}

// Round 22
// 60.859 us; speedup vs baseline: 2.0561x; 2.0561x over previous
//
#include <hip/hip_runtime.h>
#include <hip/hip_bf16.h>

#define B_ 4
#define Q_ 256
#define K_ 1024
#define D_ 256
#define NVPAD 768
#define LOG2E 1.44269504f

__device__ __forceinline__ float fexp2(float x) {
    float r; asm("v_exp_f32 %0, %1" : "=v"(r) : "v"(x)); return r;
}
__device__ __forceinline__ float frcp(float x) {
    float r; asm("v_rcp_f32 %0, %1" : "=v"(r) : "v"(x)); return r;
}

// Grid (80,4), 256 thr. 2-launch pipeline: compaction is recomputed INLINE
// (deterministic, block-local -> no cross-block race).
// x<16 : q-proj rows m0=x*64 -> qpE row-major (exp2 applied).
// x>=16: k-proj over compacted slot space; block scans the batch mask itself
//        (256-thread prefix sum) to build its 64-slot gather window.
__global__ __launch_bounds__(256) void proj_kernel(const float* __restrict__ q,
                                                   const float* __restrict__ k,
                                                   const float* __restrict__ Wq,
                                                   const float* __restrict__ Wk,
                                                   const int* __restrict__ mask,
                                                   float* __restrict__ qpE,
                                                   float* __restrict__ kpC,
                                                   float scale) {
    const int t = threadIdx.x;
    const bool isQ = blockIdx.x < 16;
    const float* A; const float* W; int m0, b = 0, nv = 0;
    __shared__ ushort s_row[64];
    __shared__ int s_wtot[4], s_woff[4], s_nv4;

    if (isQ) { A = q; W = Wq; m0 = blockIdx.x * 64; }
    else {
        const int g = (blockIdx.x - 16) * 64;
        b = g >> 10;
        m0 = g & 1023;
        A = k; W = Wk;
        // ---- inline compaction scan: thread t owns k = t*4 .. t*4+3 ----
        const int lane64 = t & 63, wv4 = t >> 6;
        const int* mb = mask + b * K_ + t * 4;
        const int b0 = (mb[0] != 0), b1 = (mb[1] != 0),
                  b2 = (mb[2] != 0), b3 = (mb[3] != 0);
        const int m4 = b0 + b1 + b2 + b3;
        int inc = m4;
#pragma unroll
        for (int d = 1; d < 64; d <<= 1) {
            int tt = __shfl_up(inc, d);
            if (lane64 >= d) inc += tt;
        }
        if (lane64 == 63) s_wtot[wv4] = inc;
        if (t < 64) s_row[t] = 0;
        __syncthreads();
        if (t < 4) {
            int off = 0;
            for (int w = 0; w < t; ++w) off += s_wtot[w];
            s_woff[t] = off;
            if (t == 3) s_nv4 = off + s_wtot[3];
        }
        __syncthreads();
        nv = s_nv4;
        if (m0 >= nv) return;                 // block-uniform exit
        int pos = s_woff[wv4] + inc - m4;     // exclusive prefix
        const int kb4 = t * 4;
        if (b0) { int sl = pos++; if (sl >= m0 && sl < m0 + 64) s_row[sl - m0] = (ushort)(kb4);     }
        if (b1) { int sl = pos++; if (sl >= m0 && sl < m0 + 64) s_row[sl - m0] = (ushort)(kb4 + 1); }
        if (b2) { int sl = pos++; if (sl >= m0 && sl < m0 + 64) s_row[sl - m0] = (ushort)(kb4 + 2); }
        if (b3) { int sl = pos++; if (sl >= m0 && sl < m0 + 64) s_row[sl - m0] = (ushort)(kb4 + 3); }
        __syncthreads();                      // s_row ready
    }

    __shared__ float As[16][65];
    __shared__ float Ws[16][64];
    const int tx = t & 15, ty = t >> 4;
    const int n0 = blockIdx.y * 64;
    const int ar = t >> 2, ac = (t & 3) * 4;
    const int wr = t >> 4, wc = (t & 15) * 4;
    float c[4][4] = {};
    for (int kb = 0; kb < 256; kb += 16) {
        __syncthreads();
        {
            const int src = isQ ? (m0 + ar) : (b * K_ + s_row[ar]);
            float4 av = *(const float4*)(A + (size_t)src * 256 + kb + ac);
            As[ac + 0][ar] = av.x; As[ac + 1][ar] = av.y;
            As[ac + 2][ar] = av.z; As[ac + 3][ar] = av.w;
        }
        float4 wvv = *(const float4*)(W + (size_t)(kb + wr) * 256 + n0 + wc);
        wvv.x *= scale; wvv.y *= scale; wvv.z *= scale; wvv.w *= scale;
        *(float4*)(&Ws[wr][wc]) = wvv;
        __syncthreads();
#pragma unroll
        for (int kk = 0; kk < 16; ++kk) {
            float4 bv = *(const float4*)(&Ws[kk][tx * 4]);
#pragma unroll
            for (int i = 0; i < 4; ++i) {
                float a = As[kk][ty * 4 + i];
                c[i][0] = fmaf(a, bv.x, c[i][0]);
                c[i][1] = fmaf(a, bv.y, c[i][1]);
                c[i][2] = fmaf(a, bv.z, c[i][2]);
                c[i][3] = fmaf(a, bv.w, c[i][3]);
            }
        }
    }
    if (isQ) {
#pragma unroll
        for (int i = 0; i < 4; ++i) {
            float4 o = make_float4(fexp2(c[i][0]), fexp2(c[i][1]),
                                   fexp2(c[i][2]), fexp2(c[i][3]));
            *(float4*)(qpE + (size_t)(m0 + ty * 4 + i) * 256 + n0 + tx * 4) = o;
        }
    } else {
        float* kpCb = kpC + (size_t)b * 64 * NVPAD * 4;
        const int e4 = (n0 + tx * 4) >> 2;
#pragma unroll
        for (int i = 0; i < 4; ++i) {
            const int sl = m0 + ty * 4 + i;
            if (sl < nv) {
                float4 o = make_float4(fexp2(c[i][0]), fexp2(c[i][1]),
                                       fexp2(c[i][2]), fexp2(c[i][3]));
                *(float4*)(kpCb + ((size_t)e4 * NVPAD + sl) * 4) = o;
            }
        }
    }
}

// Grid = 512 = B * 128 qpairs, 1024 threads = 16 waves -> 2 blocks/CU.
// R14-verbatim score/softmax/PV (best measured, 43-46 us) + inline
// compaction prologue (1024-thread prefix sum over the batch mask;
// replaces the global kidx/nvalid dependency and the compact kernel).
__global__ __launch_bounds__(1024, 2) void attn_kernel(const float* __restrict__ qpE,
                                                       const float* __restrict__ kpC,
                                                       const float* __restrict__ v,
                                                       const int* __restrict__ mask,
                                                       const float* __restrict__ wv,
                                                       float* __restrict__ out) {
    __shared__ float  s_sc[2][1024];      //  8 KB
    __shared__ ushort s_kidx[1024];       //  2 KB
    __shared__ float4 s_pv[32][64];       // 32 KB
    __shared__ float  s_inv[2];
    __shared__ int    s_wtot[16], s_woff[16], s_nvs;

    const int tid  = threadIdx.x;
    const int lane = tid & 63;
    const int wave = tid >> 6;            // 0..15
    const int sl8  = lane & 7;
    const int ec   = lane >> 3;           // 0..7

    int bid = blockIdx.x;
    bid = (bid & 7) * 64 + (bid >> 3);    // bijective XCD swizzle
    const int b  = bid >> 7;
    const int qi = bid & 127;
    const int q0 = qi * 2;

    // ---- inline compaction: block prefix-sum over mask[b][0..1023] ----
    const int mv = (mask[b * K_ + tid] != 0) ? 1 : 0;
    int incp = mv;
#pragma unroll
    for (int d = 1; d < 64; d <<= 1) {
        int tt = __shfl_up(incp, d);
        if (lane >= d) incp += tt;
    }
    if (lane == 63) s_wtot[wave] = incp;
    s_kidx[tid] = 0;
    ((float2*)s_sc)[tid] = make_float2(0.f, 0.f);
    __syncthreads();
    if (tid < 16) {
        int off = 0;
        for (int w = 0; w < tid; ++w) off += s_wtot[w];
        s_woff[tid] = off;
        if (tid == 15) s_nvs = off + s_wtot[15];
    }
    __syncthreads();
    const int nv = s_nvs;
    if (mv) s_kidx[s_woff[wave] + incp - 1] = (ushort)tid;
    __syncthreads();

    const int iters = (nv + 127) >> 7;

    const float4* Bp  = (const float4*)kpC + (size_t)b * 64 * NVPAD;
    const float*  A0g = qpE + ((size_t)(b * Q_ + q0) << 8);
    const float*  A1g = A0g + 256;

    for (int eq = 0; eq < 4; ++eq) {
        const int e0 = eq * 64 + ec * 8;
        float A0[8], A1[8], W[8];
        {
            float4 x0 = *(const float4*)(A0g + e0);
            float4 x1 = *(const float4*)(A0g + e0 + 4);
            A0[0]=x0.x; A0[1]=x0.y; A0[2]=x0.z; A0[3]=x0.w;
            A0[4]=x1.x; A0[5]=x1.y; A0[6]=x1.z; A0[7]=x1.w;
            float4 y0 = *(const float4*)(A1g + e0);
            float4 y1 = *(const float4*)(A1g + e0 + 4);
            A1[0]=y0.x; A1[1]=y0.y; A1[2]=y0.z; A1[3]=y0.w;
            A1[4]=y1.x; A1[5]=y1.y; A1[6]=y1.z; A1[7]=y1.w;
            float4 w0 = *(const float4*)(wv + e0);
            float4 w1 = *(const float4*)(wv + e0 + 4);
            W[0]=w0.x; W[1]=w0.y; W[2]=w0.z; W[3]=w0.w;
            W[4]=w1.x; W[5]=w1.y; W[6]=w1.z; W[7]=w1.w;
        }
        const float4* BpE = Bp + (size_t)(eq * 16 + ec * 2) * NVPAD;

#pragma unroll 2
        for (int i = 0; i < iters; ++i) {
            const int s = i * 128 + wave * 8 + sl8;
            float4 B0 = BpE[s];
            float4 B1 = BpE[NVPAD + s];
            float a0 = 0.f, a1 = 0.f;
            a0 = fmaf(W[0], frcp(fmaf(A0[0], B0.x, 1.f)), a0);
            a1 = fmaf(W[0], frcp(fmaf(A1[0], B0.x, 1.f)), a1);
            a0 = fmaf(W[1], frcp(fmaf(A0[1], B0.y, 1.f)), a0);
            a1 = fmaf(W[1], frcp(fmaf(A1[1], B0.y, 1.f)), a1);
            a0 = fmaf(W[2], frcp(fmaf(A0[2], B0.z, 1.f)), a0);
            a1 = fmaf(W[2], frcp(fmaf(A1[2], B0.z, 1.f)), a1);
            a0 = fmaf(W[3], frcp(fmaf(A0[3], B0.w, 1.f)), a0);
            a1 = fmaf(W[3], frcp(fmaf(A1[3], B0.w, 1.f)), a1);
            a0 = fmaf(W[4], frcp(fmaf(A0[4], B1.x, 1.f)), a0);
            a1 = fmaf(W[4], frcp(fmaf(A1[4], B1.x, 1.f)), a1);
            a0 = fmaf(W[5], frcp(fmaf(A0[5], B1.y, 1.f)), a0);
            a1 = fmaf(W[5], frcp(fmaf(A1[5], B1.y, 1.f)), a1);
            a0 = fmaf(W[6], frcp(fmaf(A0[6], B1.z, 1.f)), a0);
            a1 = fmaf(W[6], frcp(fmaf(A1[6], B1.z, 1.f)), a1);
            a0 = fmaf(W[7], frcp(fmaf(A0[7], B1.w, 1.f)), a0);
            a1 = fmaf(W[7], frcp(fmaf(A1[7], B1.w, 1.f)), a1);
            a0 += __shfl_xor(a0, 8);  a1 += __shfl_xor(a1, 8);
            a0 += __shfl_xor(a0, 16); a1 += __shfl_xor(a1, 16);
            a0 += __shfl_xor(a0, 32); a1 += __shfl_xor(a1, 32);
            if (ec == 0 && s < nv) {
                s_sc[0][s] += a0;               // single lane owns (q,s): race-free
                s_sc[1][s] += a1;
            }
        }
    }
    __syncthreads();

    // ---- softmax: wave qq < 2 handles q = qq (score = -2 * accumulated) ----
    if (wave < 2) {
        const int qq = wave;
        float mx = -3.0e38f;
        for (int j = lane; j < nv; j += 64) mx = fmaxf(mx, -2.f * s_sc[qq][j]);
#pragma unroll
        for (int off = 32; off > 0; off >>= 1) mx = fmaxf(mx, __shfl_xor(mx, off));
        float sum = 0.f;
        for (int j = lane; j < nv; j += 64) {
            float e = fexp2((-2.f * s_sc[qq][j] - mx) * LOG2E);
            s_sc[qq][j] = e;
            sum += e;
        }
#pragma unroll
        for (int off = 32; off > 0; off >>= 1) sum += __shfl_xor(sum, off);
        if (lane == 0) s_inv[qq] = frcp(sum);
    }
    __syncthreads();

    // ---- PV: thread -> (d-float4 = tid&63, k stride-16 chunk = tid>>6) ----
    {
        const int dl = tid & 63;
        const int kq = tid >> 6;
        float4 o0 = {0, 0, 0, 0}, o1 = {0, 0, 0, 0};
        const float4* v4 = (const float4*)(v + ((size_t)b * K_ << 8));
        for (int k = kq; k < nv; k += 16) {
            int vr = s_kidx[k];
            float4 vv = v4[((size_t)vr << 6) + dl];
            float p0 = s_sc[0][k], p1 = s_sc[1][k];
            o0.x = fmaf(p0, vv.x, o0.x); o0.y = fmaf(p0, vv.y, o0.y);
            o0.z = fmaf(p0, vv.z, o0.z); o0.w = fmaf(p0, vv.w, o0.w);
            o1.x = fmaf(p1, vv.x, o1.x); o1.y = fmaf(p1, vv.y, o1.y);
            o1.z = fmaf(p1, vv.z, o1.z); o1.w = fmaf(p1, vv.w, o1.w);
        }
        s_pv[kq * 2 + 0][dl] = o0;
        s_pv[kq * 2 + 1][dl] = o1;
        __syncthreads();
        if (tid < 128) {
            const int qq = tid >> 6, c = tid & 63;
            float4 s = {0, 0, 0, 0};
#pragma unroll
            for (int g = 0; g < 16; ++g) {
                float4 x = s_pv[g * 2 + qq][c];
                s.x += x.x; s.y += x.y; s.z += x.z; s.w += x.w;
            }
            const float inv = s_inv[qq];
            s.x *= inv; s.y *= inv; s.z *= inv; s.w *= inv;
            ((float4*)out)[((size_t)(b * Q_ + q0 + qq) << 6) + c] = s;
        }
    }
}

extern "C" void kernel_launch(void* const* d_in, const int* in_sizes, int n_in,
                              void* d_out, int out_size, void* d_ws, size_t ws_size,
                              hipStream_t stream) {
    const float* q    = (const float*)d_in[0];
    const float* k    = (const float*)d_in[1];
    const float* v    = (const float*)d_in[2];
    const int*   mask = (const int*)d_in[3];
    const float* Wq   = (const float*)d_in[4];
    const float* Wk   = (const float*)d_in[5];
    const float* wv   = (const float*)d_in[6];
    float* out = (float*)d_out;

    float* qpE = (float*)d_ws;                               // 1 MB
    float* kpC = qpE + (size_t)B_ * Q_ * D_;                 // 3 MB

    const float c2 = 2.885390082f;  // 2*log2(e)

    proj_kernel<<<dim3(80, 4), 256, 0, stream>>>(q, k, Wq, Wk, mask, qpE, kpC, c2);
    attn_kernel<<<dim3(512), 1024, 0, stream>>>(qpE, kpC, v, mask, wv, out);
}

// Round 24
// 60.086 us; speedup vs baseline: 2.0826x; 1.0129x over previous
//
#include <hip/hip_runtime.h>
#include <hip/hip_bf16.h>

#define B_ 4
#define Q_ 256
#define K_ 1024
#define D_ 256
#define NVPAD 768
#define LOG2E 1.44269504f

__device__ __forceinline__ float fexp2(float x) {
    float r; asm("v_exp_f32 %0, %1" : "=v"(r) : "v"(x)); return r;
}
__device__ __forceinline__ float frcp(float x) {
    float r; asm("v_rcp_f32 %0, %1" : "=v"(r) : "v"(x)); return r;
}

// Grid (80,8), 256 thr, 64-row x 32-col tiles (2x blocks vs R22 -> 2x
// latency hiding). Inline compaction (deterministic, block-local).
// x<16 : q-proj rows m0=x*64 -> qpE row-major (exp2 applied).
// x>=16: k-proj over compacted slot space; block scans the batch mask
//        itself to build its 64-slot gather window.
__global__ __launch_bounds__(256) void proj_kernel(const float* __restrict__ q,
                                                   const float* __restrict__ k,
                                                   const float* __restrict__ Wq,
                                                   const float* __restrict__ Wk,
                                                   const int* __restrict__ mask,
                                                   float* __restrict__ qpE,
                                                   float* __restrict__ kpC,
                                                   float scale) {
    const int t = threadIdx.x;
    const bool isQ = blockIdx.x < 16;
    const float* A; const float* W; int m0, b = 0, nv = 0;
    __shared__ ushort s_row[64];
    __shared__ int s_wtot[4], s_woff[4], s_nv4;

    if (isQ) { A = q; W = Wq; m0 = blockIdx.x * 64; }
    else {
        const int g = (blockIdx.x - 16) * 64;
        b = g >> 10;
        m0 = g & 1023;
        A = k; W = Wk;
        // ---- inline compaction scan: thread t owns k = t*4 .. t*4+3 ----
        const int lane64 = t & 63, wv4 = t >> 6;
        const int* mb = mask + b * K_ + t * 4;
        const int b0 = (mb[0] != 0), b1 = (mb[1] != 0),
                  b2 = (mb[2] != 0), b3 = (mb[3] != 0);
        const int m4 = b0 + b1 + b2 + b3;
        int inc = m4;
#pragma unroll
        for (int d = 1; d < 64; d <<= 1) {
            int tt = __shfl_up(inc, d);
            if (lane64 >= d) inc += tt;
        }
        if (lane64 == 63) s_wtot[wv4] = inc;
        if (t < 64) s_row[t] = 0;
        __syncthreads();
        if (t < 4) {
            int off = 0;
            for (int w = 0; w < t; ++w) off += s_wtot[w];
            s_woff[t] = off;
            if (t == 3) s_nv4 = off + s_wtot[3];
        }
        __syncthreads();
        nv = s_nv4;
        if (m0 >= nv) return;                 // block-uniform exit
        int pos = s_woff[wv4] + inc - m4;     // exclusive prefix
        const int kb4 = t * 4;
        if (b0) { int sl = pos++; if (sl >= m0 && sl < m0 + 64) s_row[sl - m0] = (ushort)(kb4);     }
        if (b1) { int sl = pos++; if (sl >= m0 && sl < m0 + 64) s_row[sl - m0] = (ushort)(kb4 + 1); }
        if (b2) { int sl = pos++; if (sl >= m0 && sl < m0 + 64) s_row[sl - m0] = (ushort)(kb4 + 2); }
        if (b3) { int sl = pos++; if (sl >= m0 && sl < m0 + 64) s_row[sl - m0] = (ushort)(kb4 + 3); }
        __syncthreads();                      // s_row ready
    }

    __shared__ float As[16][65];
    __shared__ float Ws[16][32];
    const int tx = t & 7;            // 8 col-groups x 4 = 32 cols
    const int ty = t >> 3;           // 32 row-groups x 2 rows
    const int n0 = blockIdx.y * 32;
    const int ar = t >> 2, ac = (t & 3) * 4;
    const int wr = t >> 4, wc = (t & 15) * 2;
    float c[2][4] = {};
    for (int kb = 0; kb < 256; kb += 16) {
        __syncthreads();
        {
            const int src = isQ ? (m0 + ar) : (b * K_ + s_row[ar]);
            float4 av = *(const float4*)(A + (size_t)src * 256 + kb + ac);
            As[ac + 0][ar] = av.x; As[ac + 1][ar] = av.y;
            As[ac + 2][ar] = av.z; As[ac + 3][ar] = av.w;
        }
        {
            float2 wvv = *(const float2*)(W + (size_t)(kb + wr) * 256 + n0 + wc);
            wvv.x *= scale; wvv.y *= scale;
            *(float2*)(&Ws[wr][wc]) = wvv;
        }
        __syncthreads();
#pragma unroll
        for (int kk = 0; kk < 16; ++kk) {
            float4 bv = *(const float4*)(&Ws[kk][tx * 4]);
            float a0 = As[kk][ty * 2 + 0];
            float a1 = As[kk][ty * 2 + 1];
            c[0][0] = fmaf(a0, bv.x, c[0][0]);
            c[0][1] = fmaf(a0, bv.y, c[0][1]);
            c[0][2] = fmaf(a0, bv.z, c[0][2]);
            c[0][3] = fmaf(a0, bv.w, c[0][3]);
            c[1][0] = fmaf(a1, bv.x, c[1][0]);
            c[1][1] = fmaf(a1, bv.y, c[1][1]);
            c[1][2] = fmaf(a1, bv.z, c[1][2]);
            c[1][3] = fmaf(a1, bv.w, c[1][3]);
        }
    }
    if (isQ) {
#pragma unroll
        for (int i = 0; i < 2; ++i) {
            float4 o = make_float4(fexp2(c[i][0]), fexp2(c[i][1]),
                                   fexp2(c[i][2]), fexp2(c[i][3]));
            *(float4*)(qpE + (size_t)(m0 + ty * 2 + i) * 256 + n0 + tx * 4) = o;
        }
    } else {
        float* kpCb = kpC + (size_t)b * 64 * NVPAD * 4;
        const int e4 = (n0 + tx * 4) >> 2;
#pragma unroll
        for (int i = 0; i < 2; ++i) {
            const int sl = m0 + ty * 2 + i;
            if (sl < nv) {
                float4 o = make_float4(fexp2(c[i][0]), fexp2(c[i][1]),
                                       fexp2(c[i][2]), fexp2(c[i][3]));
                *(float4*)(kpCb + ((size_t)e4 * NVPAD + sl) * 4) = o;
            }
        }
    }
}

// Grid = 512 = B * 128 qpairs, 1024 threads = 16 waves -> 2 blocks/CU.
// R14-verbatim score/softmax/PV (best measured, 43-46 us) + inline
// compaction prologue (1024-thread prefix sum over the batch mask).
__global__ __launch_bounds__(1024, 2) void attn_kernel(const float* __restrict__ qpE,
                                                       const float* __restrict__ kpC,
                                                       const float* __restrict__ v,
                                                       const int* __restrict__ mask,
                                                       const float* __restrict__ wv,
                                                       float* __restrict__ out) {
    __shared__ float  s_sc[2][1024];      //  8 KB
    __shared__ ushort s_kidx[1024];       //  2 KB
    __shared__ float4 s_pv[32][64];       // 32 KB
    __shared__ float  s_inv[2];
    __shared__ int    s_wtot[16], s_woff[16], s_nvs;

    const int tid  = threadIdx.x;
    const int lane = tid & 63;
    const int wave = tid >> 6;            // 0..15
    const int sl8  = lane & 7;
    const int ec   = lane >> 3;           // 0..7

    int bid = blockIdx.x;
    bid = (bid & 7) * 64 + (bid >> 3);    // bijective XCD swizzle
    const int b  = bid >> 7;
    const int qi = bid & 127;
    const int q0 = qi * 2;

    // ---- inline compaction: block prefix-sum over mask[b][0..1023] ----
    const int mv = (mask[b * K_ + tid] != 0) ? 1 : 0;
    int incp = mv;
#pragma unroll
    for (int d = 1; d < 64; d <<= 1) {
        int tt = __shfl_up(incp, d);
        if (lane >= d) incp += tt;
    }
    if (lane == 63) s_wtot[wave] = incp;
    s_kidx[tid] = 0;
    ((float2*)s_sc)[tid] = make_float2(0.f, 0.f);
    __syncthreads();
    if (tid < 16) {
        int off = 0;
        for (int w = 0; w < tid; ++w) off += s_wtot[w];
        s_woff[tid] = off;
        if (tid == 15) s_nvs = off + s_wtot[15];
    }
    __syncthreads();
    const int nv = s_nvs;
    if (mv) s_kidx[s_woff[wave] + incp - 1] = (ushort)tid;
    __syncthreads();

    const int iters = (nv + 127) >> 7;

    const float4* Bp  = (const float4*)kpC + (size_t)b * 64 * NVPAD;
    const float*  A0g = qpE + ((size_t)(b * Q_ + q0) << 8);
    const float*  A1g = A0g + 256;

    for (int eq = 0; eq < 4; ++eq) {
        const int e0 = eq * 64 + ec * 8;
        float A0[8], A1[8], W[8];
        {
            float4 x0 = *(const float4*)(A0g + e0);
            float4 x1 = *(const float4*)(A0g + e0 + 4);
            A0[0]=x0.x; A0[1]=x0.y; A0[2]=x0.z; A0[3]=x0.w;
            A0[4]=x1.x; A0[5]=x1.y; A0[6]=x1.z; A0[7]=x1.w;
            float4 y0 = *(const float4*)(A1g + e0);
            float4 y1 = *(const float4*)(A1g + e0 + 4);
            A1[0]=y0.x; A1[1]=y0.y; A1[2]=y0.z; A1[3]=y0.w;
            A1[4]=y1.x; A1[5]=y1.y; A1[6]=y1.z; A1[7]=y1.w;
            float4 w0 = *(const float4*)(wv + e0);
            float4 w1 = *(const float4*)(wv + e0 + 4);
            W[0]=w0.x; W[1]=w0.y; W[2]=w0.z; W[3]=w0.w;
            W[4]=w1.x; W[5]=w1.y; W[6]=w1.z; W[7]=w1.w;
        }
        const float4* BpE = Bp + (size_t)(eq * 16 + ec * 2) * NVPAD;

#pragma unroll 2
        for (int i = 0; i < iters; ++i) {
            const int s = i * 128 + wave * 8 + sl8;
            float4 B0 = BpE[s];
            float4 B1 = BpE[NVPAD + s];
            float a0 = 0.f, a1 = 0.f;
            a0 = fmaf(W[0], frcp(fmaf(A0[0], B0.x, 1.f)), a0);
            a1 = fmaf(W[0], frcp(fmaf(A1[0], B0.x, 1.f)), a1);
            a0 = fmaf(W[1], frcp(fmaf(A0[1], B0.y, 1.f)), a0);
            a1 = fmaf(W[1], frcp(fmaf(A1[1], B0.y, 1.f)), a1);
            a0 = fmaf(W[2], frcp(fmaf(A0[2], B0.z, 1.f)), a0);
            a1 = fmaf(W[2], frcp(fmaf(A1[2], B0.z, 1.f)), a1);
            a0 = fmaf(W[3], frcp(fmaf(A0[3], B0.w, 1.f)), a0);
            a1 = fmaf(W[3], frcp(fmaf(A1[3], B0.w, 1.f)), a1);
            a0 = fmaf(W[4], frcp(fmaf(A0[4], B1.x, 1.f)), a0);
            a1 = fmaf(W[4], frcp(fmaf(A1[4], B1.x, 1.f)), a1);
            a0 = fmaf(W[5], frcp(fmaf(A0[5], B1.y, 1.f)), a0);
            a1 = fmaf(W[5], frcp(fmaf(A1[5], B1.y, 1.f)), a1);
            a0 = fmaf(W[6], frcp(fmaf(A0[6], B1.z, 1.f)), a0);
            a1 = fmaf(W[6], frcp(fmaf(A1[6], B1.z, 1.f)), a1);
            a0 = fmaf(W[7], frcp(fmaf(A0[7], B1.w, 1.f)), a0);
            a1 = fmaf(W[7], frcp(fmaf(A1[7], B1.w, 1.f)), a1);
            a0 += __shfl_xor(a0, 8);  a1 += __shfl_xor(a1, 8);
            a0 += __shfl_xor(a0, 16); a1 += __shfl_xor(a1, 16);
            a0 += __shfl_xor(a0, 32); a1 += __shfl_xor(a1, 32);
            if (ec == 0 && s < nv) {
                s_sc[0][s] += a0;               // single lane owns (q,s): race-free
                s_sc[1][s] += a1;
            }
        }
    }
    __syncthreads();

    // ---- softmax: wave qq < 2 handles q = qq (score = -2 * accumulated) ----
    if (wave < 2) {
        const int qq = wave;
        float mx = -3.0e38f;
        for (int j = lane; j < nv; j += 64) mx = fmaxf(mx, -2.f * s_sc[qq][j]);
#pragma unroll
        for (int off = 32; off > 0; off >>= 1) mx = fmaxf(mx, __shfl_xor(mx, off));
        float sum = 0.f;
        for (int j = lane; j < nv; j += 64) {
            float e = fexp2((-2.f * s_sc[qq][j] - mx) * LOG2E);
            s_sc[qq][j] = e;
            sum += e;
        }
#pragma unroll
        for (int off = 32; off > 0; off >>= 1) sum += __shfl_xor(sum, off);
        if (lane == 0) s_inv[qq] = frcp(sum);
    }
    __syncthreads();

    // ---- PV: thread -> (d-float4 = tid&63, k stride-16 chunk = tid>>6) ----
    {
        const int dl = tid & 63;
        const int kq = tid >> 6;
        float4 o0 = {0, 0, 0, 0}, o1 = {0, 0, 0, 0};
        const float4* v4 = (const float4*)(v + ((size_t)b * K_ << 8));
        for (int kk = kq; kk < nv; kk += 16) {
            int vr = s_kidx[kk];
            float4 vv = v4[((size_t)vr << 6) + dl];
            float p0 = s_sc[0][kk], p1 = s_sc[1][kk];
            o0.x = fmaf(p0, vv.x, o0.x); o0.y = fmaf(p0, vv.y, o0.y);
            o0.z = fmaf(p0, vv.z, o0.z); o0.w = fmaf(p0, vv.w, o0.w);
            o1.x = fmaf(p1, vv.x, o1.x); o1.y = fmaf(p1, vv.y, o1.y);
            o1.z = fmaf(p1, vv.z, o1.z); o1.w = fmaf(p1, vv.w, o1.w);
        }
        s_pv[kq * 2 + 0][dl] = o0;
        s_pv[kq * 2 + 1][dl] = o1;
        __syncthreads();
        if (tid < 128) {
            const int qq = tid >> 6, c = tid & 63;
            float4 s = {0, 0, 0, 0};
#pragma unroll
            for (int g = 0; g < 16; ++g) {
                float4 x = s_pv[g * 2 + qq][c];
                s.x += x.x; s.y += x.y; s.z += x.z; s.w += x.w;
            }
            const float inv = s_inv[qq];
            s.x *= inv; s.y *= inv; s.z *= inv; s.w *= inv;
            ((float4*)out)[((size_t)(b * Q_ + q0 + qq) << 6) + c] = s;
        }
    }
}

extern "C" void kernel_launch(void* const* d_in, const int* in_sizes, int n_in,
                              void* d_out, int out_size, void* d_ws, size_t ws_size,
                              hipStream_t stream) {
    const float* q    = (const float*)d_in[0];
    const float* k    = (const float*)d_in[1];
    const float* v    = (const float*)d_in[2];
    const int*   mask = (const int*)d_in[3];
    const float* Wq   = (const float*)d_in[4];
    const float* Wk   = (const float*)d_in[5];
    const float* wv   = (const float*)d_in[6];
    float* out = (float*)d_out;

    float* qpE = (float*)d_ws;                               // 1 MB
    float* kpC = qpE + (size_t)B_ * Q_ * D_;                 // 3 MB

    const float c2 = 2.885390082f;  // 2*log2(e)

    proj_kernel<<<dim3(80, 8), 256, 0, stream>>>(q, k, Wq, Wk, mask, qpE, kpC, c2);
    attn_kernel<<<dim3(512), 1024, 0, stream>>>(qpE, kpC, v, mask, wv, out);
}